// Round 1
// baseline (451.841 us; speedup 1.0000x reference)
//
#include <hip/hip_runtime.h>
#include <math.h>

#define NB 2
#define QN 8192
#define DIM 256
#define NHEADS 8
#define HDIM 32
#define S_TOT 5440   // 4096+1024+256+64

// ---------------------------------------------------------------------------
// Value projection: vals[b][loff+s][d] = sum_c feat[b][c][s] * Wv[c][d] + bv[d]
// One block = (batch b, 16 spatial positions), blockDim = 256 (= d)
// ---------------------------------------------------------------------------
__global__ __launch_bounds__(256) void val_proj_kernel(
    const float* __restrict__ f, const float* __restrict__ Wv,
    const float* __restrict__ bv, float* __restrict__ vals,
    int HW, int lvl_off) {
  const int ntile = HW / 16;
  const int b = blockIdx.x / ntile;
  const int s0 = (blockIdx.x % ntile) * 16;
  const int tid = threadIdx.x;

  __shared__ float As[16][DIM];   // [spatial][channel]

  {
    // thread tid = channel c; read 16 consecutive spatial floats
    const float* fp = f + ((size_t)b * DIM + tid) * (size_t)HW + s0;
    float4 v[4];
#pragma unroll
    for (int j = 0; j < 4; ++j) v[j] = *(const float4*)(fp + 4 * j);
#pragma unroll
    for (int j = 0; j < 4; ++j) {
      As[4 * j + 0][tid] = v[j].x;
      As[4 * j + 1][tid] = v[j].y;
      As[4 * j + 2][tid] = v[j].z;
      As[4 * j + 3][tid] = v[j].w;
    }
  }
  __syncthreads();

  float acc[16];
#pragma unroll
  for (int r = 0; r < 16; ++r) acc[r] = 0.f;

  for (int k = 0; k < DIM; k += 4) {
    float w0 = Wv[(size_t)(k + 0) * DIM + tid];
    float w1 = Wv[(size_t)(k + 1) * DIM + tid];
    float w2 = Wv[(size_t)(k + 2) * DIM + tid];
    float w3 = Wv[(size_t)(k + 3) * DIM + tid];
#pragma unroll
    for (int r = 0; r < 16; ++r) {
      float4 a = *(const float4*)&As[r][k];
      acc[r] = fmaf(a.x, w0, acc[r]);
      acc[r] = fmaf(a.y, w1, acc[r]);
      acc[r] = fmaf(a.z, w2, acc[r]);
      acc[r] = fmaf(a.w, w3, acc[r]);
    }
  }

  const float bb = bv[tid];
#pragma unroll
  for (int r = 0; r < 16; ++r) {
    vals[((size_t)b * S_TOT + lvl_off + s0 + r) * DIM + tid] = acc[r] + bb;
  }
}

// ---------------------------------------------------------------------------
// Generic row-major GEMM: C[M x NOUT] = A[M x 256] @ W[256 x NOUT] + bias
// blockDim = NOUT, 16 rows per block.
// ---------------------------------------------------------------------------
template <int NOUT>
__global__ __launch_bounds__(NOUT) void qproj_kernel(
    const float* __restrict__ A, const float* __restrict__ Wm,
    const float* __restrict__ bias, float* __restrict__ C) {
  const int r0 = blockIdx.x * 16;
  const int tid = threadIdx.x;

  __shared__ float As[16][DIM];

  for (int i = tid; i < 16 * (DIM / 4); i += NOUT) {
    int r = i >> 6;          // /64 float4s per row
    int k4 = i & 63;
    ((float4*)As[r])[k4] = ((const float4*)(A + (size_t)(r0 + r) * DIM))[k4];
  }
  __syncthreads();

  float acc[16];
#pragma unroll
  for (int r = 0; r < 16; ++r) acc[r] = 0.f;

  for (int k = 0; k < DIM; k += 4) {
    float w0 = Wm[(size_t)(k + 0) * NOUT + tid];
    float w1 = Wm[(size_t)(k + 1) * NOUT + tid];
    float w2 = Wm[(size_t)(k + 2) * NOUT + tid];
    float w3 = Wm[(size_t)(k + 3) * NOUT + tid];
#pragma unroll
    for (int r = 0; r < 16; ++r) {
      float4 a = *(const float4*)&As[r][k];
      acc[r] = fmaf(a.x, w0, acc[r]);
      acc[r] = fmaf(a.y, w1, acc[r]);
      acc[r] = fmaf(a.z, w2, acc[r]);
      acc[r] = fmaf(a.w, w3, acc[r]);
    }
  }

  const float bb = bias[tid];
#pragma unroll
  for (int r = 0; r < 16; ++r) {
    C[(size_t)(r0 + r) * NOUT + tid] = acc[r] + bb;
  }
}

// ---------------------------------------------------------------------------
// Sampling + softmax + weighted sum.
// One block per (b,q); thread = (h, hd) with h = tid>>5, hd = tid&31.
// out1[bq][h*32+hd] = sum_{l,p} aw[l,p] * bilinear(vals_level_l, loc)
// ---------------------------------------------------------------------------
__global__ __launch_bounds__(256) void sample_kernel(
    const float* __restrict__ vals, const float* __restrict__ offb,
    const float* __restrict__ attnb, const float* __restrict__ refp,
    float* __restrict__ out1) {
  const int bq = blockIdx.x;              // 0 .. N*Q-1
  const int b = bq >> 13;                 // /8192
  const int tid = threadIdx.x;
  const int h = tid >> 5;

  const float rx = refp[(size_t)bq * 2 + 0];
  const float ry = refp[(size_t)bq * 2 + 1];

  // softmax over 16 logits (redundant across the 32 lanes of a head; broadcast)
  const float* al = attnb + (size_t)bq * 128 + h * 16;
  float logit[16];
  float m = -1e30f;
#pragma unroll
  for (int i = 0; i < 16; ++i) {
    logit[i] = al[i];
    m = fmaxf(m, logit[i]);
  }
  float s = 0.f;
#pragma unroll
  for (int i = 0; i < 16; ++i) {
    logit[i] = expf(logit[i] - m);
    s += logit[i];
  }
  const float inv = 1.0f / s;

  const float* ob = offb + (size_t)bq * 256 + h * 32;

  float acc = 0.f;
#pragma unroll
  for (int l = 0; l < 4; ++l) {
    const int Wl = (l == 0) ? 64 : (l == 1) ? 32 : (l == 2) ? 16 : 8;
    const int loff = (l == 0) ? 0 : (l == 1) ? 4096 : (l == 2) ? 5120 : 5376;
    const float* vbase = vals + ((size_t)b * S_TOT + loff) * DIM + tid;
#pragma unroll
    for (int p = 0; p < 4; ++p) {
      const float ox = ob[l * 8 + p * 2 + 0];
      const float oy = ob[l * 8 + p * 2 + 1];
      const float px = (rx + ox) * (float)Wl - 0.5f;
      const float py = (ry + oy) * (float)Wl - 0.5f;
      const float fx = floorf(px), fy = floorf(py);
      const float wx = px - fx, wy = py - fy;
      const int x0 = (int)fx, y0 = (int)fy;

      const bool xv0 = (x0 >= 0) & (x0 < Wl);
      const bool xv1 = (x0 + 1 >= 0) & (x0 + 1 < Wl);
      const bool yv0 = (y0 >= 0) & (y0 < Wl);
      const bool yv1 = (y0 + 1 >= 0) & (y0 + 1 < Wl);

      float v00 = 0.f, v10 = 0.f, v01 = 0.f, v11 = 0.f;
      if (yv0) {
        const float* row = vbase + (size_t)(y0 * Wl) * DIM;
        if (xv0) v00 = row[(size_t)x0 * DIM];
        if (xv1) v10 = row[(size_t)(x0 + 1) * DIM];
      }
      if (yv1) {
        const float* row = vbase + (size_t)((y0 + 1) * Wl) * DIM;
        if (xv0) v01 = row[(size_t)x0 * DIM];
        if (xv1) v11 = row[(size_t)(x0 + 1) * DIM];
      }
      const float bil = (1.f - wx) * (1.f - wy) * v00 + wx * (1.f - wy) * v10 +
                        (1.f - wx) * wy * v01 + wx * wy * v11;
      acc = fmaf(logit[l * 4 + p] * inv, bil, acc);
    }
  }

  out1[(size_t)bq * DIM + tid] = acc;
}

// ---------------------------------------------------------------------------
extern "C" void kernel_launch(void* const* d_in, const int* in_sizes, int n_in,
                              void* d_out, int out_size, void* d_ws, size_t ws_size,
                              hipStream_t stream) {
  const float* query = (const float*)d_in[0];
  const float* feat[4] = {(const float*)d_in[1], (const float*)d_in[2],
                          (const float*)d_in[3], (const float*)d_in[4]};
  const float* refp  = (const float*)d_in[5];
  const float* W_off = (const float*)d_in[6];
  const float* b_off = (const float*)d_in[7];
  const float* W_attn = (const float*)d_in[8];
  const float* b_attn = (const float*)d_in[9];
  const float* W_val = (const float*)d_in[10];
  const float* b_val = (const float*)d_in[11];
  const float* W_out = (const float*)d_in[12];
  const float* b_out = (const float*)d_in[13];
  float* out = (float*)d_out;

  // workspace layout (floats)
  float* ws = (float*)d_ws;
  float* vals = ws;                                   // N*S_TOT*256 = 2,785,280
  float* offb = vals + (size_t)NB * S_TOT * DIM;      // N*Q*256    = 4,194,304
  float* attnb = offb + (size_t)NB * QN * 256;        // N*Q*128    = 2,097,152

  const int HWs[4]  = {4096, 1024, 256, 64};
  const int loff[4] = {0, 4096, 5120, 5376};

  // 1. value projection per level
  for (int l = 0; l < 4; ++l) {
    val_proj_kernel<<<NB * (HWs[l] / 16), 256, 0, stream>>>(
        feat[l], W_val, b_val, vals, HWs[l], loff[l]);
  }

  // 2. offset projection  (M = N*Q = 16384 rows)
  qproj_kernel<256><<<(NB * QN) / 16, 256, 0, stream>>>(query, W_off, b_off, offb);

  // 3. attention-logit projection
  qproj_kernel<128><<<(NB * QN) / 16, 128, 0, stream>>>(query, W_attn, b_attn, attnb);

  // 4. sampling + softmax + weighted sum -> staged in d_out
  sample_kernel<<<NB * QN, 256, 0, stream>>>(vals, offb, attnb, refp, out);

  // 5. output projection, in-place on d_out (each block stages its own 16 rows
  //    in LDS before writing them; no cross-block row sharing)
  qproj_kernel<256><<<(NB * QN) / 16, 256, 0, stream>>>(out, W_out, b_out, out);
}

// Round 3
// 279.140 us; speedup vs baseline: 1.6187x; 1.6187x over previous
//
#include <hip/hip_runtime.h>
#include <math.h>

#define NB 2
#define QN 8192
#define DIM 256
#define S_TOT 5440   // 4096+1024+256+64

typedef unsigned int uint32;

__device__ __forceinline__ unsigned short f2bf_rn(float x) {
  union { float f; uint32 u; } v; v.f = x;
  uint32 u = v.u;
  return (unsigned short)((u + 0x7fffu + ((u >> 16) & 1u)) >> 16);
}
__device__ __forceinline__ float bflo(uint32 u) {
  union { uint32 u; float f; } v; v.u = u << 16; return v.f;
}
__device__ __forceinline__ float bfhi(uint32 u) {
  union { uint32 u; float f; } v; v.u = u & 0xffff0000u; return v.f;
}

// ---------------------------------------------------------------------------
// Value projection -> bf16 vals[b][s][d]. Block = (b, 16 spatial), thread = d.
// feat reads wave-uniform -> s_load; W reads coalesced.
// ---------------------------------------------------------------------------
__global__ __launch_bounds__(256) void val_proj_kernel(
    const float* __restrict__ f, const float* __restrict__ Wv,
    const float* __restrict__ bv, unsigned short* __restrict__ vals,
    int HW, int lvl_off) {
  const int ntile = HW / 16;
  const int b = blockIdx.x / ntile;
  const int s0 = (blockIdx.x % ntile) * 16;
  const int tid = threadIdx.x;

  float acc[16];
#pragma unroll
  for (int r = 0; r < 16; ++r) acc[r] = 0.f;

  const float* fb = f + (size_t)b * DIM * HW + s0;
#pragma unroll 4
  for (int c = 0; c < DIM; ++c) {
    const float w = Wv[(size_t)c * DIM + tid];
    const float* fp = fb + (size_t)c * HW;
#pragma unroll
    for (int r = 0; r < 16; ++r) acc[r] = fmaf(fp[r], w, acc[r]);
  }

  const float bb = bv[tid];
#pragma unroll
  for (int r = 0; r < 16; ++r) {
    vals[((size_t)b * S_TOT + lvl_off + s0 + r) * DIM + tid] =
        f2bf_rn(acc[r] + bb);
  }
}

// ---------------------------------------------------------------------------
// GEMM: C[M x NOUT] = A[M x 256] @ W[256 x NOUT] + bias. 16 rows per block.
// A reads wave-uniform -> s_load; pure-FMA inner loop. NEVER use in-place
// (no barrier between A reads and C writes -> inter-wave race).
// ---------------------------------------------------------------------------
template <int NOUT>
__global__ __launch_bounds__(NOUT) void qproj_kernel(
    const float* __restrict__ A, const float* __restrict__ Wm,
    const float* __restrict__ bias, float* __restrict__ C) {
  const int r0 = blockIdx.x * 16;
  const int tid = threadIdx.x;

  float acc[16];
#pragma unroll
  for (int r = 0; r < 16; ++r) acc[r] = 0.f;

  const float* Ab = A + (size_t)r0 * DIM;
#pragma unroll 4
  for (int k = 0; k < DIM; ++k) {
    const float w = Wm[(size_t)k * NOUT + tid];
#pragma unroll
    for (int r = 0; r < 16; ++r) acc[r] = fmaf(Ab[(size_t)r * DIM + k], w, acc[r]);
  }

  const float bb = bias[tid];
#pragma unroll
  for (int r = 0; r < 16; ++r) {
    C[(size_t)(r0 + r) * NOUT + tid] = acc[r] + bb;
  }
}

// ---------------------------------------------------------------------------
// Sampling + softmax + weighted sum, bf16 values.
// Block = 2 queries; per query 8 heads x 16 lanes.
// Phase 1: lane g computes point g's softmax weight + bilinear params once,
//          stores {float4 w, int4 byte-offset} to padded LDS.
//          All reads of offb[bq][*] complete here (before __syncthreads).
// Phase 2: lane g accumulates channels (2g,2g+1) over 16 points x 4 corners,
//          then writes the result OVER offb[bq][*] (row owned exclusively by
//          this block-half; deterministic since offb is rebuilt every call).
// ---------------------------------------------------------------------------
__global__ __launch_bounds__(256) void sample_kernel(
    const unsigned short* __restrict__ vals, float* offb,
    const float* __restrict__ attnb, const float* __restrict__ refp) {
  const int tid = threadIdx.x;
  const int g = tid & 15;        // point index (phase1) / channel pair (phase2)
  const int grp = tid >> 4;      // 0..15 : (half, head)
  const int h = grp & 7;
  const int half = tid >> 7;
  const int bq = blockIdx.x * 2 + half;
  const int b = bq >> 13;

  __shared__ float4 wts[16][17];  // padded stride kills bank conflicts
  __shared__ int4 idxs[16][17];

  // ---- phase 1 ----
  const float rx = refp[(size_t)bq * 2 + 0];
  const float ry = refp[(size_t)bq * 2 + 1];

  float logit = attnb[(size_t)bq * 128 + h * 16 + g];
  float m = logit;
#pragma unroll
  for (int mask = 1; mask < 16; mask <<= 1)
    m = fmaxf(m, __shfl_xor(m, mask, 16));
  const float e = __expf(logit - m);
  float ssum = e;
#pragma unroll
  for (int mask = 1; mask < 16; mask <<= 1)
    ssum += __shfl_xor(ssum, mask, 16);
  const float aw = e / ssum;

  const float2 o2 = *(const float2*)(offb + (size_t)bq * 256 + h * 32 + g * 2);
  const int l = g >> 2;
  const int Wl = 64 >> l;                               // 64,32,16,8
  const int loff = (l == 0) ? 0 : (l == 1) ? 4096 : (l == 2) ? 5120 : 5376;

  const float px = (rx + o2.x) * (float)Wl - 0.5f;
  const float py = (ry + o2.y) * (float)Wl - 0.5f;
  const float fx = floorf(px), fy = floorf(py);
  const float wx = px - fx, wy = py - fy;
  const int x0 = (int)fx, y0 = (int)fy;
  const int x1 = x0 + 1, y1 = y0 + 1;
  const float vx0 = (x0 >= 0 && x0 < Wl) ? 1.f : 0.f;
  const float vx1 = (x1 >= 0 && x1 < Wl) ? 1.f : 0.f;
  const float vy0 = (y0 >= 0 && y0 < Wl) ? 1.f : 0.f;
  const float vy1 = (y1 >= 0 && y1 < Wl) ? 1.f : 0.f;
  const int cx0 = min(max(x0, 0), Wl - 1), cx1 = min(max(x1, 0), Wl - 1);
  const int cy0 = min(max(y0, 0), Wl - 1), cy1 = min(max(y1, 0), Wl - 1);
  const int base = b * S_TOT + loff;
  idxs[grp][g] = make_int4((base + cy0 * Wl + cx0) * 512,
                           (base + cy0 * Wl + cx1) * 512,
                           (base + cy1 * Wl + cx0) * 512,
                           (base + cy1 * Wl + cx1) * 512);
  wts[grp][g] = make_float4(aw * (1.f - wx) * (1.f - wy) * vx0 * vy0,
                            aw * wx * (1.f - wy) * vx1 * vy0,
                            aw * (1.f - wx) * wy * vx0 * vy1,
                            aw * wx * wy * vx1 * vy1);
  __syncthreads();   // all offb reads for this block complete before this

  // ---- phase 2 ----
  const char* vb = (const char*)vals + (h * 64 + g * 4);
  float acc0 = 0.f, acc1 = 0.f;
#pragma unroll
  for (int i = 0; i < 16; ++i) {
    const float4 w = wts[grp][i];
    const int4 id = idxs[grp][i];
    const uint32 u00 = *(const uint32*)(vb + id.x);
    const uint32 u10 = *(const uint32*)(vb + id.y);
    const uint32 u01 = *(const uint32*)(vb + id.z);
    const uint32 u11 = *(const uint32*)(vb + id.w);
    acc0 = fmaf(bflo(u00), w.x, acc0); acc1 = fmaf(bfhi(u00), w.x, acc1);
    acc0 = fmaf(bflo(u10), w.y, acc0); acc1 = fmaf(bfhi(u10), w.y, acc1);
    acc0 = fmaf(bflo(u01), w.z, acc0); acc1 = fmaf(bfhi(u01), w.z, acc1);
    acc0 = fmaf(bflo(u11), w.w, acc0); acc1 = fmaf(bfhi(u11), w.w, acc1);
  }
  float2 r; r.x = acc0; r.y = acc1;
  *(float2*)(offb + (size_t)bq * 256 + h * 32 + g * 2) = r;  // overwrite own row
}

// ---------------------------------------------------------------------------
extern "C" void kernel_launch(void* const* d_in, const int* in_sizes, int n_in,
                              void* d_out, int out_size, void* d_ws, size_t ws_size,
                              hipStream_t stream) {
  const float* query = (const float*)d_in[0];
  const float* feat[4] = {(const float*)d_in[1], (const float*)d_in[2],
                          (const float*)d_in[3], (const float*)d_in[4]};
  const float* refp  = (const float*)d_in[5];
  const float* W_off = (const float*)d_in[6];
  const float* b_off = (const float*)d_in[7];
  const float* W_attn = (const float*)d_in[8];
  const float* b_attn = (const float*)d_in[9];
  const float* W_val = (const float*)d_in[10];
  const float* b_val = (const float*)d_in[11];
  const float* W_out = (const float*)d_in[12];
  const float* b_out = (const float*)d_in[13];
  float* out = (float*)d_out;

  // workspace layout (~30.7 MB)
  unsigned short* vals = (unsigned short*)d_ws;            // N*S_TOT*256 bf16 = 5.6 MB
  float* offb = (float*)(vals + (size_t)NB * S_TOT * DIM); // N*Q*256 f32 = 16.8 MB (reused as sample output)
  float* attnb = offb + (size_t)NB * QN * 256;             // N*Q*128 f32 = 8.4 MB

  const int HWs[4]  = {4096, 1024, 256, 64};
  const int loff[4] = {0, 4096, 5120, 5376};

  for (int l = 0; l < 4; ++l) {
    val_proj_kernel<<<NB * (HWs[l] / 16), 256, 0, stream>>>(
        feat[l], W_val, b_val, vals, HWs[l], loff[l]);
  }

  qproj_kernel<256><<<(NB * QN) / 16, 256, 0, stream>>>(query, W_off, b_off, offb);
  qproj_kernel<128><<<(NB * QN) / 16, 128, 0, stream>>>(query, W_attn, b_attn, attnb);

  // sample writes its output over offb (race-free: see kernel comment)
  sample_kernel<<<(NB * QN) / 2, 256, 0, stream>>>(vals, offb, attnb, refp);

  // output projection: ws -> d_out (no aliasing)
  qproj_kernel<256><<<(NB * QN) / 16, 256, 0, stream>>>(offb, W_out, b_out, out);
}

// Round 4
// 113.631 us; speedup vs baseline: 3.9764x; 2.4565x over previous
//
#include <hip/hip_runtime.h>
#include <math.h>

#define NB 2
#define QN 8192
#define DIM 256
#define S_TOT 5440   // 4096+1024+256+64

typedef unsigned int uint32;
typedef unsigned short u16;
typedef __attribute__((ext_vector_type(8))) short sh8;    // 8 bf16 (4 VGPR) MFMA A/B frag
typedef __attribute__((ext_vector_type(4))) float f32x4;  // MFMA C/D frag
typedef __attribute__((ext_vector_type(4))) uint32 u32x4; // 16B staging

__device__ __forceinline__ u16 f2bf_rn(float x) {
  union { float f; uint32 u; } v; v.f = x;
  uint32 u = v.u;
  return (u16)((u + 0x7fffu + ((u >> 16) & 1u)) >> 16);
}
__device__ __forceinline__ float bf2f(u16 h) {
  union { uint32 u; float f; } v; v.u = ((uint32)h) << 16; return v.f;
}
__device__ __forceinline__ float bflo(uint32 u) {
  union { uint32 u; float f; } v; v.u = u << 16; return v.f;
}
__device__ __forceinline__ float bfhi(uint32 u) {
  union { uint32 u; float f; } v; v.u = u & 0xffff0000u; return v.f;
}

// ---------------------------------------------------------------------------
// Transpose + convert: src f32 [256][S] -> dst bf16 [S][256].
// SPLIT=1 additionally writes the bf16 residual (hi/lo split) to d1.
// Used for feat->featT, W_off/W_attn->Wcat_t(hi,lo), W_val->Wval_t, W_out.
// ---------------------------------------------------------------------------
template <int SPLIT>
__global__ __launch_bounds__(256) void tconv_kernel(
    const float* __restrict__ src, u16* __restrict__ d0, u16* __restrict__ d1,
    int S, int src_bs, int dst_bs) {
  __shared__ float tile[32][33];
  const int tx = threadIdx.x & 31, ty = threadIdx.x >> 5;  // ty 0..7
  const int s0 = blockIdx.x * 32, c0 = blockIdx.y * 32;
  const int b = blockIdx.z;
  const float* sp = src + (size_t)b * src_bs;
#pragma unroll
  for (int j = 0; j < 4; ++j) {
    int c = c0 + ty + j * 8;
    tile[ty + j * 8][tx] = sp[(size_t)c * S + s0 + tx];  // tile[c_local][s_local]
  }
  __syncthreads();
#pragma unroll
  for (int j = 0; j < 4; ++j) {
    const int srow = s0 + ty + j * 8;
    const float v = tile[tx][ty + j * 8];  // transpose read, stride 33: no conflicts
    const u16 hi = f2bf_rn(v);
    const size_t o = (size_t)b * dst_bs + (size_t)srow * 256 + c0 + tx;
    d0[o] = hi;
    if constexpr (SPLIT) d1[o] = f2bf_rn(v - bf2f(hi));
  }
}

// ---------------------------------------------------------------------------
// query f32 -> q_hi,q_lo bf16 (elementwise, 8 per thread)
// ---------------------------------------------------------------------------
__global__ __launch_bounds__(256) void convq_kernel(
    const float* __restrict__ q, u16* __restrict__ hi, u16* __restrict__ lo) {
  const size_t i = ((size_t)blockIdx.x * 256 + threadIdx.x) * 8;
  const float4 v0 = *(const float4*)(q + i);
  const float4 v1 = *(const float4*)(q + i + 4);
  const float vv[8] = {v0.x, v0.y, v0.z, v0.w, v1.x, v1.y, v1.z, v1.w};
  u16 h[8], l[8];
#pragma unroll
  for (int j = 0; j < 8; ++j) {
    h[j] = f2bf_rn(vv[j]);
    l[j] = f2bf_rn(vv[j] - bf2f(h[j]));
  }
  *(u32x4*)(hi + i) = *(const u32x4*)h;
  *(u32x4*)(lo + i) = *(const u32x4*)l;
}

// ---------------------------------------------------------------------------
// Single-precision-bf16 MFMA GEMM, whole K=256 staged.
// C[M x 256] = A[M x 256] @ Bt[256 x 256]^T + bias, C written as bf16 (vals).
// 64x64 tile, 4 waves (2x2), each wave 32x32 = 2x2 16x16 frags.
// LDS XOR swizzle slot^(row&7): frag ds_read_b128 2-way (free).
// ---------------------------------------------------------------------------
__global__ __launch_bounds__(256) void gemm_single_kernel(
    const u16* __restrict__ A, const u16* __restrict__ Bt,
    const float* __restrict__ bias, u16* __restrict__ C) {
  __shared__ u16 As[64][256];
  __shared__ u16 Bs[64][256];
  const int tid = threadIdx.x;
  const size_t r0 = (size_t)blockIdx.x * 64;
  const size_t c0 = (size_t)blockIdx.y * 64;

  {  // stage: 8 iters x 256 threads x 16B per tile
    const u16* ga = A + r0 * 256;
    const u16* gb = Bt + c0 * 256;
    const int row = tid >> 5, slot = tid & 31;
#pragma unroll
    for (int i = 0; i < 8; ++i) {
      const int r = i * 8 + row;
      const int ph = (slot & 24) | ((slot ^ r) & 7);
      *(u32x4*)&As[r][ph * 8] = *(const u32x4*)(ga + (size_t)r * 256 + slot * 8);
      *(u32x4*)&Bs[r][ph * 8] = *(const u32x4*)(gb + (size_t)r * 256 + slot * 8);
    }
  }
  __syncthreads();

  const int wid = tid >> 6, lane = tid & 63;
  const int wr = (wid >> 1) * 32, wc = (wid & 1) * 32;
  const int l15 = lane & 15, l4 = lane >> 4;

  f32x4 acc[2][2] = {};
#pragma unroll
  for (int ks = 0; ks < 8; ++ks) {
    const int slot = ks * 4 + l4;
    sh8 a[2], b[2];
#pragma unroll
    for (int m = 0; m < 2; ++m) {
      const int r = wr + m * 16 + l15;
      const int ph = (slot & 24) | ((slot ^ r) & 7);
      a[m] = *(const sh8*)&As[r][ph * 8];
    }
#pragma unroll
    for (int n = 0; n < 2; ++n) {
      const int r = wc + n * 16 + l15;
      const int ph = (slot & 24) | ((slot ^ r) & 7);
      b[n] = *(const sh8*)&Bs[r][ph * 8];
    }
#pragma unroll
    for (int m = 0; m < 2; ++m)
#pragma unroll
      for (int n = 0; n < 2; ++n)
        acc[m][n] = __builtin_amdgcn_mfma_f32_16x16x32_bf16(a[m], b[n], acc[m][n], 0, 0, 0);
  }

  // C/D: col = lane&15, row = (lane>>4)*4 + reg  [m89 verified]
#pragma unroll
  for (int m = 0; m < 2; ++m)
#pragma unroll
    for (int n = 0; n < 2; ++n)
#pragma unroll
      for (int r = 0; r < 4; ++r) {
        const size_t row = r0 + wr + m * 16 + l4 * 4 + r;
        const size_t col = c0 + wc + n * 16 + l15;
        C[row * 256 + col] = f2bf_rn(acc[m][n][r] + bias[col]);
      }
}

// ---------------------------------------------------------------------------
// Split (hi/lo) bf16 MFMA GEMM ~ fp32 accuracy: C = Ah*Bh + Ah*Bl + Al*Bh.
// K staged in two 128-halves (4 x 16KB = 64KB LDS), 64x64 tile, 4 waves.
// MODE 0: N=384; cols<256 -> f32 out0+bias0 (offsets into d_out);
//         cols>=256 -> bf16 out1+bias1 (attn logits).  MODE 1: f32 out0+bias0.
// ---------------------------------------------------------------------------
template <int MODE>
__global__ __launch_bounds__(256) void gemm_split_kernel(
    const u16* __restrict__ Agh, const u16* __restrict__ Agl,
    const u16* __restrict__ Bgh, const u16* __restrict__ Bgl,
    const float* __restrict__ bias0, const float* __restrict__ bias1,
    float* __restrict__ out0, u16* __restrict__ out1) {
  __shared__ u16 Ah[64][128], Al[64][128], Bh[64][128], Bl[64][128];
  const int tid = threadIdx.x;
  const size_t r0 = (size_t)blockIdx.x * 64;
  const size_t c0 = (size_t)blockIdx.y * 64;

  const int wid = tid >> 6, lane = tid & 63;
  const int wr = (wid >> 1) * 32, wc = (wid & 1) * 32;
  const int l15 = lane & 15, l4 = lane >> 4;

  f32x4 acc[2][2] = {};

#pragma unroll
  for (int kh = 0; kh < 2; ++kh) {
    {  // stage the k-half of all 4 matrices
      const u16* ga_h = Agh + r0 * 256 + kh * 128;
      const u16* ga_l = Agl + r0 * 256 + kh * 128;
      const u16* gb_h = Bgh + c0 * 256 + kh * 128;
      const u16* gb_l = Bgl + c0 * 256 + kh * 128;
      const int srow = tid >> 4, sslot = tid & 15;
#pragma unroll
      for (int i = 0; i < 4; ++i) {
        const int r = i * 16 + srow;
        const int ph = (sslot & 8) | ((sslot ^ r) & 7);
        *(u32x4*)&Ah[r][ph * 8] = *(const u32x4*)(ga_h + (size_t)r * 256 + sslot * 8);
        *(u32x4*)&Al[r][ph * 8] = *(const u32x4*)(ga_l + (size_t)r * 256 + sslot * 8);
        *(u32x4*)&Bh[r][ph * 8] = *(const u32x4*)(gb_h + (size_t)r * 256 + sslot * 8);
        *(u32x4*)&Bl[r][ph * 8] = *(const u32x4*)(gb_l + (size_t)r * 256 + sslot * 8);
      }
    }
    __syncthreads();

#pragma unroll
    for (int ks = 0; ks < 4; ++ks) {
      const int slot = ks * 4 + l4;
      sh8 ah[2], al[2], bh[2], bl[2];
#pragma unroll
      for (int m = 0; m < 2; ++m) {
        const int r = wr + m * 16 + l15;
        const int ph = (slot & 8) | ((slot ^ r) & 7);
        ah[m] = *(const sh8*)&Ah[r][ph * 8];
        al[m] = *(const sh8*)&Al[r][ph * 8];
      }
#pragma unroll
      for (int n = 0; n < 2; ++n) {
        const int r = wc + n * 16 + l15;
        const int ph = (slot & 8) | ((slot ^ r) & 7);
        bh[n] = *(const sh8*)&Bh[r][ph * 8];
        bl[n] = *(const sh8*)&Bl[r][ph * 8];
      }
#pragma unroll
      for (int m = 0; m < 2; ++m)
#pragma unroll
        for (int n = 0; n < 2; ++n) {
          acc[m][n] = __builtin_amdgcn_mfma_f32_16x16x32_bf16(ah[m], bh[n], acc[m][n], 0, 0, 0);
          acc[m][n] = __builtin_amdgcn_mfma_f32_16x16x32_bf16(ah[m], bl[n], acc[m][n], 0, 0, 0);
          acc[m][n] = __builtin_amdgcn_mfma_f32_16x16x32_bf16(al[m], bh[n], acc[m][n], 0, 0, 0);
        }
    }
    __syncthreads();  // protect LDS restage (WAR)
  }

#pragma unroll
  for (int m = 0; m < 2; ++m)
#pragma unroll
    for (int n = 0; n < 2; ++n)
#pragma unroll
      for (int r = 0; r < 4; ++r) {
        const size_t row = r0 + wr + m * 16 + l4 * 4 + r;
        const size_t col = c0 + wc + n * 16 + l15;
        const float v = acc[m][n][r];
        if constexpr (MODE == 0) {
          if (c0 < 256)
            out0[row * 256 + col] = v + bias0[col];
          else
            out1[row * 128 + (col - 256)] = f2bf_rn(v + bias1[col - 256]);
        } else {
          out0[row * 256 + col] = v + bias0[col];
        }
      }
}

// ---------------------------------------------------------------------------
// Sampling + softmax + weighted sum (round-3 structure).
// Inputs: vals bf16, qoff f32 (=d_out, offsets), attnb bf16 logits, refp.
// Outputs: samp hi/lo bf16 (feeds split out-proj GEMM).
// ---------------------------------------------------------------------------
__global__ __launch_bounds__(256) void sample_kernel(
    const u16* __restrict__ vals, const float* __restrict__ qoff,
    const u16* __restrict__ attnb, const float* __restrict__ refp,
    u16* __restrict__ shi, u16* __restrict__ slo) {
  const int tid = threadIdx.x;
  const int g = tid & 15;
  const int grp = tid >> 4;
  const int h = grp & 7;
  const int half = tid >> 7;
  const int bq = blockIdx.x * 2 + half;
  const int b = bq >> 13;

  __shared__ float4 wts[16][17];
  __shared__ int4 idxs[16][17];

  // ---- phase 1: per-point params ----
  const float rx = refp[(size_t)bq * 2 + 0];
  const float ry = refp[(size_t)bq * 2 + 1];

  float logit = bf2f(attnb[(size_t)bq * 128 + h * 16 + g]);
  float m = logit;
#pragma unroll
  for (int mask = 1; mask < 16; mask <<= 1)
    m = fmaxf(m, __shfl_xor(m, mask, 16));
  const float e = __expf(logit - m);
  float ssum = e;
#pragma unroll
  for (int mask = 1; mask < 16; mask <<= 1)
    ssum += __shfl_xor(ssum, mask, 16);
  const float aw = e / ssum;

  const float2 o2 = *(const float2*)(qoff + (size_t)bq * 256 + h * 32 + g * 2);
  const int l = g >> 2;
  const int Wl = 64 >> l;
  const int loff = (l == 0) ? 0 : (l == 1) ? 4096 : (l == 2) ? 5120 : 5376;

  const float px = (rx + o2.x) * (float)Wl - 0.5f;
  const float py = (ry + o2.y) * (float)Wl - 0.5f;
  const float fx = floorf(px), fy = floorf(py);
  const float wx = px - fx, wy = py - fy;
  const int x0 = (int)fx, y0 = (int)fy;
  const int x1 = x0 + 1, y1 = y0 + 1;
  const float vx0 = (x0 >= 0 && x0 < Wl) ? 1.f : 0.f;
  const float vx1 = (x1 >= 0 && x1 < Wl) ? 1.f : 0.f;
  const float vy0 = (y0 >= 0 && y0 < Wl) ? 1.f : 0.f;
  const float vy1 = (y1 >= 0 && y1 < Wl) ? 1.f : 0.f;
  const int cx0 = min(max(x0, 0), Wl - 1), cx1 = min(max(x1, 0), Wl - 1);
  const int cy0 = min(max(y0, 0), Wl - 1), cy1 = min(max(y1, 0), Wl - 1);
  const int base = b * S_TOT + loff;
  idxs[grp][g] = make_int4((base + cy0 * Wl + cx0) * 512,
                           (base + cy0 * Wl + cx1) * 512,
                           (base + cy1 * Wl + cx0) * 512,
                           (base + cy1 * Wl + cx1) * 512);
  wts[grp][g] = make_float4(aw * (1.f - wx) * (1.f - wy) * vx0 * vy0,
                            aw * wx * (1.f - wy) * vx1 * vy0,
                            aw * (1.f - wx) * wy * vx0 * vy1,
                            aw * wx * wy * vx1 * vy1);
  __syncthreads();

  // ---- phase 2: gather + accumulate (channels 2g,2g+1 of head h) ----
  const char* vb = (const char*)vals + (h * 64 + g * 4);
  float acc0 = 0.f, acc1 = 0.f;
#pragma unroll
  for (int i = 0; i < 16; ++i) {
    const float4 w = wts[grp][i];
    const int4 id = idxs[grp][i];
    const uint32 u00 = *(const uint32*)(vb + id.x);
    const uint32 u10 = *(const uint32*)(vb + id.y);
    const uint32 u01 = *(const uint32*)(vb + id.z);
    const uint32 u11 = *(const uint32*)(vb + id.w);
    acc0 = fmaf(bflo(u00), w.x, acc0); acc1 = fmaf(bfhi(u00), w.x, acc1);
    acc0 = fmaf(bflo(u10), w.y, acc0); acc1 = fmaf(bfhi(u10), w.y, acc1);
    acc0 = fmaf(bflo(u01), w.z, acc0); acc1 = fmaf(bfhi(u01), w.z, acc1);
    acc0 = fmaf(bflo(u11), w.w, acc0); acc1 = fmaf(bfhi(u11), w.w, acc1);
  }
  const u16 h0 = f2bf_rn(acc0), h1 = f2bf_rn(acc1);
  const u16 l0 = f2bf_rn(acc0 - bf2f(h0)), l1 = f2bf_rn(acc1 - bf2f(h1));
  const size_t o = (size_t)bq * 256 + h * 32 + g * 2;
  *(uint32*)(shi + o) = (uint32)h0 | ((uint32)h1 << 16);
  *(uint32*)(slo + o) = (uint32)l0 | ((uint32)l1 << 16);
}

// ---------------------------------------------------------------------------
extern "C" void kernel_launch(void* const* d_in, const int* in_sizes, int n_in,
                              void* d_out, int out_size, void* d_ws, size_t ws_size,
                              hipStream_t stream) {
  const float* query = (const float*)d_in[0];
  const float* feat[4] = {(const float*)d_in[1], (const float*)d_in[2],
                          (const float*)d_in[3], (const float*)d_in[4]};
  const float* refp  = (const float*)d_in[5];
  const float* W_off = (const float*)d_in[6];
  const float* b_off = (const float*)d_in[7];
  const float* W_attn = (const float*)d_in[8];
  const float* b_attn = (const float*)d_in[9];
  const float* W_val = (const float*)d_in[10];
  const float* b_val = (const float*)d_in[11];
  const float* W_out = (const float*)d_in[12];
  const float* b_out = (const float*)d_in[13];
  float* out = (float*)d_out;

  // ---- workspace layout (u16 units; total 28.7 MB) ----
  u16* ws = (u16*)d_ws;
  u16* featT  = ws;                        // [10880][256] bf16 (5.57MB)
  u16* attnb  = featT;                     // ALIAS: [16384][128] bf16; written by
                                           // GEMM1 strictly after GEMM2 consumed featT
  u16* vals   = featT + (size_t)NB * S_TOT * 256;   // [10880][256] bf16
  u16* q_hi   = vals + (size_t)NB * S_TOT * 256;    // [16384][256] bf16
  u16* q_lo   = q_hi + (size_t)NB * QN * 256;       // [16384][256] bf16
  u16* samp_h = q_hi;                      // ALIAS: sample runs after GEMM1 read q
  u16* samp_l = q_lo;
  u16* Wcat_h = q_lo + (size_t)NB * QN * 256;       // [384][256]
  u16* Wcat_l = Wcat_h + 384 * 256;
  u16* Wval_t = Wcat_l + 384 * 256;                 // [256][256]
  u16* Wout_h = Wval_t + 256 * 256;
  u16* Wout_l = Wout_h + 256 * 256;

  const int HWs[4]  = {4096, 1024, 256, 64};
  const int loff[4] = {0, 4096, 5120, 5376};

  // 1. transposes / conversions
  for (int l = 0; l < 4; ++l) {
    tconv_kernel<0><<<dim3(HWs[l] / 32, 8, NB), 256, 0, stream>>>(
        feat[l], featT + (size_t)loff[l] * 256, nullptr,
        HWs[l], 256 * HWs[l], S_TOT * 256);
  }
  tconv_kernel<1><<<dim3(8, 8, 1), 256, 0, stream>>>(W_off, Wcat_h, Wcat_l, 256, 0, 0);
  tconv_kernel<1><<<dim3(4, 8, 1), 256, 0, stream>>>(W_attn, Wcat_h + 256 * 256,
                                                     Wcat_l + 256 * 256, 128, 0, 0);
  tconv_kernel<0><<<dim3(8, 8, 1), 256, 0, stream>>>(W_val, Wval_t, nullptr, 256, 0, 0);
  tconv_kernel<1><<<dim3(8, 8, 1), 256, 0, stream>>>(W_out, Wout_h, Wout_l, 256, 0, 0);
  convq_kernel<<<2048, 256, 0, stream>>>(query, q_hi, q_lo);

  // 2. value projection (single bf16): featT @ Wval_t -> vals bf16
  gemm_single_kernel<<<dim3((NB * S_TOT) / 64, 4), 256, 0, stream>>>(
      featT, Wval_t, b_val, vals);

  // 3. offset+logit projection (split ~fp32): q @ Wcat -> d_out(off f32) + attnb(bf16)
  gemm_split_kernel<0><<<dim3((NB * QN) / 64, 6), 256, 0, stream>>>(
      q_hi, q_lo, Wcat_h, Wcat_l, b_off, b_attn, out, attnb);

  // 4. sampling -> samp hi/lo (over q_hi/q_lo; GEMM1 already consumed them)
  sample_kernel<<<(NB * QN) / 2, 256, 0, stream>>>(vals, out, attnb, refp,
                                                   samp_h, samp_l);

  // 5. out projection (split ~fp32): samp @ Wout -> d_out f32
  gemm_split_kernel<1><<<dim3((NB * QN) / 64, 4), 256, 0, stream>>>(
      samp_h, samp_l, Wout_h, Wout_l, b_out, nullptr, out, nullptr);
}

// Round 5
// 95.801 us; speedup vs baseline: 4.7164x; 1.1861x over previous
//
#include <hip/hip_runtime.h>
#include <math.h>

#define NB 2
#define QN 8192
#define DIM 256
#define S_TOT 5440   // 4096+1024+256+64

typedef unsigned int uint32;
typedef _Float16 f16;
typedef __attribute__((ext_vector_type(8))) _Float16 h8;   // MFMA A/B frag (4 VGPR)
typedef __attribute__((ext_vector_type(4))) _Float16 h4;   // 8B vector
typedef __attribute__((ext_vector_type(2))) _Float16 h2;
typedef __attribute__((ext_vector_type(4))) float f32x4;   // MFMA C/D frag
typedef __attribute__((ext_vector_type(4))) uint32 u32x4;  // 16B staging

// ---------------------------------------------------------------------------
// Transpose + convert: src f32 [256][S] -> dst fp16 [S][256].
// feat->featT, W_off/W_attn->Wcat_t, W_val->Wval_t, W_out->Wout_t.
// ---------------------------------------------------------------------------
__global__ __launch_bounds__(256) void tconv_kernel(
    const float* __restrict__ src, f16* __restrict__ dst,
    int S, int src_bs, int dst_bs) {
  __shared__ float tile[32][33];
  const int tx = threadIdx.x & 31, ty = threadIdx.x >> 5;  // ty 0..7
  const int s0 = blockIdx.x * 32, c0 = blockIdx.y * 32;
  const int b = blockIdx.z;
  const float* sp = src + (size_t)b * src_bs;
#pragma unroll
  for (int j = 0; j < 4; ++j) {
    int c = c0 + ty + j * 8;
    tile[ty + j * 8][tx] = sp[(size_t)c * S + s0 + tx];
  }
  __syncthreads();
#pragma unroll
  for (int j = 0; j < 4; ++j) {
    const int srow = s0 + ty + j * 8;
    const float v = tile[tx][ty + j * 8];  // stride-33 transpose read: conflict-free
    dst[(size_t)b * dst_bs + (size_t)srow * 256 + c0 + tx] = (f16)v;
  }
}

// ---------------------------------------------------------------------------
// query f32 -> fp16 (elementwise, 8 per thread)
// ---------------------------------------------------------------------------
__global__ __launch_bounds__(256) void convq_kernel(
    const float* __restrict__ q, f16* __restrict__ o) {
  const size_t i = ((size_t)blockIdx.x * 256 + threadIdx.x) * 8;
  const float4 v0 = *(const float4*)(q + i);
  const float4 v1 = *(const float4*)(q + i + 4);
  h8 r = {(f16)v0.x, (f16)v0.y, (f16)v0.z, (f16)v0.w,
          (f16)v1.x, (f16)v1.y, (f16)v1.z, (f16)v1.w};
  *(h8*)(o + i) = r;
}

// ---------------------------------------------------------------------------
// fp16 MFMA GEMM: C[M x N] = A[M x 256] @ Bt[N x 256]^T + bias.
// 64x64 tile, 4 waves (2x2), wave = 32x32 = 2x2 16x16x32 frags, whole-K LDS.
// XOR swizzle slot^(row&7): frag ds_read_b128 conflict-free-ish (2-way, free).
// MODE 0: fp16 out o0 (stride 256), bias0          [vals]
// MODE 1: c0<256 -> fp16 o0 (stride 256, bias0=offsets);
//         c0>=256 -> fp16 o1 (stride 128, bias1=logits)
// MODE 2: f32 out o2 (stride 256), bias0           [final]
// ---------------------------------------------------------------------------
template <int MODE>
__global__ __launch_bounds__(256) void gemm_f16_kernel(
    const f16* __restrict__ A, const f16* __restrict__ Bt,
    const float* __restrict__ bias0, const float* __restrict__ bias1,
    f16* __restrict__ o0, f16* __restrict__ o1, float* __restrict__ o2) {
  __shared__ f16 As[64][256];
  __shared__ f16 Bs[64][256];
  const int tid = threadIdx.x;
  const size_t r0 = (size_t)blockIdx.x * 64;
  const size_t c0 = (size_t)blockIdx.y * 64;

  {  // stage both 64x256 tiles: 8 iters x 256 threads x 16B
    const f16* ga = A + r0 * 256;
    const f16* gb = Bt + c0 * 256;
    const int row = tid >> 5, slot = tid & 31;
#pragma unroll
    for (int i = 0; i < 8; ++i) {
      const int r = i * 8 + row;
      const int ph = (slot & 24) | ((slot ^ r) & 7);
      *(u32x4*)&As[r][ph * 8] = *(const u32x4*)(ga + (size_t)r * 256 + slot * 8);
      *(u32x4*)&Bs[r][ph * 8] = *(const u32x4*)(gb + (size_t)r * 256 + slot * 8);
    }
  }
  __syncthreads();

  const int wid = tid >> 6, lane = tid & 63;
  const int wr = (wid >> 1) * 32, wc = (wid & 1) * 32;
  const int l15 = lane & 15, l4 = lane >> 4;

  f32x4 acc[2][2] = {};
#pragma unroll
  for (int ks = 0; ks < 8; ++ks) {
    const int slot = ks * 4 + l4;
    h8 a[2], b[2];
#pragma unroll
    for (int m = 0; m < 2; ++m) {
      const int r = wr + m * 16 + l15;
      const int ph = (slot & 24) | ((slot ^ r) & 7);
      a[m] = *(const h8*)&As[r][ph * 8];
    }
#pragma unroll
    for (int n = 0; n < 2; ++n) {
      const int r = wc + n * 16 + l15;
      const int ph = (slot & 24) | ((slot ^ r) & 7);
      b[n] = *(const h8*)&Bs[r][ph * 8];
    }
#pragma unroll
    for (int m = 0; m < 2; ++m)
#pragma unroll
      for (int n = 0; n < 2; ++n)
        acc[m][n] = __builtin_amdgcn_mfma_f32_16x16x32_f16(a[m], b[n], acc[m][n], 0, 0, 0);
  }

  // C/D: col = lane&15, row = (lane>>4)*4 + reg  [verified r4]
#pragma unroll
  for (int m = 0; m < 2; ++m)
#pragma unroll
    for (int n = 0; n < 2; ++n)
#pragma unroll
      for (int r = 0; r < 4; ++r) {
        const size_t row = r0 + wr + m * 16 + l4 * 4 + r;
        const size_t col = c0 + wc + n * 16 + l15;
        const float v = acc[m][n][r];
        if constexpr (MODE == 0) {
          o0[row * 256 + col] = (f16)(v + bias0[col]);
        } else if constexpr (MODE == 1) {
          if (c0 < 256)
            o0[row * 256 + col] = (f16)(v + bias0[col]);
          else
            o1[row * 128 + (col - 256)] = (f16)(v + bias1[col - 256]);
        } else {
          o2[row * 256 + col] = v + bias0[col];
        }
      }
}

// ---------------------------------------------------------------------------
// Sampling + softmax + weighted sum, fp16 values.
// Block = 2 queries; per query 8 heads x 16 lanes (grp).
// Phase 1: lane g = point g: softmax weight + bilinear {float4 w, int4 byteoff}
//          into padded LDS (one copy per (query,head)).
// Phase 2: lane (c=g&7, ph=g>>3): channels 4c..4c+3, points ph*8..ph*8+7;
//          8B gathers; __shfl_xor(8) combines the two point-halves;
//          ph==0 lanes store 4 fp16 channels.
// ---------------------------------------------------------------------------
__global__ __launch_bounds__(256) void sample_kernel(
    const f16* __restrict__ vals, const f16* __restrict__ offb,
    const f16* __restrict__ attnb, const float* __restrict__ refp,
    f16* __restrict__ samp) {
  const int tid = threadIdx.x;
  const int g = tid & 15;
  const int grp = tid >> 4;
  const int h = grp & 7;
  const int half = tid >> 7;
  const int bq = blockIdx.x * 2 + half;
  const int b = bq >> 13;

  __shared__ float4 wts[16][17];
  __shared__ int4 idxs[16][17];

  // ---- phase 1 ----
  const float rx = refp[(size_t)bq * 2 + 0];
  const float ry = refp[(size_t)bq * 2 + 1];

  float logit = (float)attnb[(size_t)bq * 128 + h * 16 + g];
  float m = logit;
#pragma unroll
  for (int mask = 1; mask < 16; mask <<= 1)
    m = fmaxf(m, __shfl_xor(m, mask, 16));
  const float e = __expf(logit - m);
  float ssum = e;
#pragma unroll
  for (int mask = 1; mask < 16; mask <<= 1)
    ssum += __shfl_xor(ssum, mask, 16);
  const float aw = e / ssum;

  const h2 ov = *(const h2*)(offb + (size_t)bq * 256 + h * 32 + g * 2);
  const int l = g >> 2;
  const int Wl = 64 >> l;
  const int loff = (l == 0) ? 0 : (l == 1) ? 4096 : (l == 2) ? 5120 : 5376;

  const float px = (rx + (float)ov[0]) * (float)Wl - 0.5f;
  const float py = (ry + (float)ov[1]) * (float)Wl - 0.5f;
  const float fx = floorf(px), fy = floorf(py);
  const float wx = px - fx, wy = py - fy;
  const int x0 = (int)fx, y0 = (int)fy;
  const int x1 = x0 + 1, y1 = y0 + 1;
  const float vx0 = (x0 >= 0 && x0 < Wl) ? 1.f : 0.f;
  const float vx1 = (x1 >= 0 && x1 < Wl) ? 1.f : 0.f;
  const float vy0 = (y0 >= 0 && y0 < Wl) ? 1.f : 0.f;
  const float vy1 = (y1 >= 0 && y1 < Wl) ? 1.f : 0.f;
  const int cx0 = min(max(x0, 0), Wl - 1), cx1 = min(max(x1, 0), Wl - 1);
  const int cy0 = min(max(y0, 0), Wl - 1), cy1 = min(max(y1, 0), Wl - 1);
  const int base = b * S_TOT + loff;
  idxs[grp][g] = make_int4((base + cy0 * Wl + cx0) * 512,
                           (base + cy0 * Wl + cx1) * 512,
                           (base + cy1 * Wl + cx0) * 512,
                           (base + cy1 * Wl + cx1) * 512);
  wts[grp][g] = make_float4(aw * (1.f - wx) * (1.f - wy) * vx0 * vy0,
                            aw * wx * (1.f - wy) * vx1 * vy0,
                            aw * (1.f - wx) * wy * vx0 * vy1,
                            aw * wx * wy * vx1 * vy1);
  __syncthreads();

  // ---- phase 2 ----
  const int c = g & 7, ph = g >> 3;
  const char* vb = (const char*)vals + (h * 64 + c * 8);
  float a0 = 0.f, a1 = 0.f, a2 = 0.f, a3 = 0.f;
#pragma unroll
  for (int i = 0; i < 8; ++i) {
    const int pt = ph * 8 + i;
    const float4 w = wts[grp][pt];
    const int4 id = idxs[grp][pt];
    const h4 v00 = *(const h4*)(vb + id.x);
    const h4 v10 = *(const h4*)(vb + id.y);
    const h4 v01 = *(const h4*)(vb + id.z);
    const h4 v11 = *(const h4*)(vb + id.w);
    a0 = fmaf((float)v00[0], w.x, a0); a1 = fmaf((float)v00[1], w.x, a1);
    a2 = fmaf((float)v00[2], w.x, a2); a3 = fmaf((float)v00[3], w.x, a3);
    a0 = fmaf((float)v10[0], w.y, a0); a1 = fmaf((float)v10[1], w.y, a1);
    a2 = fmaf((float)v10[2], w.y, a2); a3 = fmaf((float)v10[3], w.y, a3);
    a0 = fmaf((float)v01[0], w.z, a0); a1 = fmaf((float)v01[1], w.z, a1);
    a2 = fmaf((float)v01[2], w.z, a2); a3 = fmaf((float)v01[3], w.z, a3);
    a0 = fmaf((float)v11[0], w.w, a0); a1 = fmaf((float)v11[1], w.w, a1);
    a2 = fmaf((float)v11[2], w.w, a2); a3 = fmaf((float)v11[3], w.w, a3);
  }
  a0 += __shfl_xor(a0, 8); a1 += __shfl_xor(a1, 8);
  a2 += __shfl_xor(a2, 8); a3 += __shfl_xor(a3, 8);
  if (ph == 0) {
    h4 r = {(f16)a0, (f16)a1, (f16)a2, (f16)a3};
    *(h4*)(samp + (size_t)bq * 256 + h * 32 + c * 4) = r;
  }
}

// ---------------------------------------------------------------------------
extern "C" void kernel_launch(void* const* d_in, const int* in_sizes, int n_in,
                              void* d_out, int out_size, void* d_ws, size_t ws_size,
                              hipStream_t stream) {
  const float* query = (const float*)d_in[0];
  const float* feat[4] = {(const float*)d_in[1], (const float*)d_in[2],
                          (const float*)d_in[3], (const float*)d_in[4]};
  const float* refp  = (const float*)d_in[5];
  const float* W_off = (const float*)d_in[6];
  const float* b_off = (const float*)d_in[7];
  const float* W_attn = (const float*)d_in[8];
  const float* b_attn = (const float*)d_in[9];
  const float* W_val = (const float*)d_in[10];
  const float* b_val = (const float*)d_in[11];
  const float* W_out = (const float*)d_in[12];
  const float* b_out = (const float*)d_in[13];
  float* out = (float*)d_out;

  // ---- workspace layout (f16 units; ~28.4 MB) ----
  f16* ws = (f16*)d_ws;
  f16* featT  = ws;                                  // [10880][256]  5.57MB
  f16* attnb  = featT;                               // ALIAS [16384][128]: GEMM1
                                                     // writes after GEMM2 read featT
  f16* vals   = featT + (size_t)NB * S_TOT * 256;    // [10880][256]  5.57MB
  f16* q16    = vals + (size_t)NB * S_TOT * 256;     // [16384][256]  8.4MB
  f16* samp   = q16;                                 // ALIAS: sample after GEMM1 read q16
  f16* offb   = q16 + (size_t)NB * QN * 256;         // [16384][256]  8.4MB
  f16* Wcat_t = offb + (size_t)NB * QN * 256;        // [384][256]
  f16* Wval_t = Wcat_t + 384 * 256;                  // [256][256]
  f16* Wout_t = Wval_t + 256 * 256;                  // [256][256]

  const int HWs[4]  = {4096, 1024, 256, 64};
  const int loff[4] = {0, 4096, 5120, 5376};

  // 1. transposes / conversions
  for (int l = 0; l < 4; ++l) {
    tconv_kernel<<<dim3(HWs[l] / 32, 8, NB), 256, 0, stream>>>(
        feat[l], featT + (size_t)loff[l] * 256, HWs[l], 256 * HWs[l], S_TOT * 256);
  }
  tconv_kernel<<<dim3(8, 8, 1), 256, 0, stream>>>(W_off, Wcat_t, 256, 0, 0);
  tconv_kernel<<<dim3(4, 8, 1), 256, 0, stream>>>(W_attn, Wcat_t + 256 * 256, 128, 0, 0);
  tconv_kernel<<<dim3(8, 8, 1), 256, 0, stream>>>(W_val, Wval_t, 256, 0, 0);
  tconv_kernel<<<dim3(8, 8, 1), 256, 0, stream>>>(W_out, Wout_t, 256, 0, 0);
  convq_kernel<<<2048, 256, 0, stream>>>(query, q16);

  // 2. value projection: featT @ Wval_t + b_val -> vals fp16
  gemm_f16_kernel<0><<<dim3((NB * S_TOT) / 64, 4), 256, 0, stream>>>(
      featT, Wval_t, b_val, nullptr, vals, nullptr, nullptr);

  // 3. offset+logit projection: q16 @ Wcat_t -> offb fp16 + attnb fp16
  gemm_f16_kernel<1><<<dim3((NB * QN) / 64, 6), 256, 0, stream>>>(
      q16, Wcat_t, b_off, b_attn, offb, attnb, nullptr);

  // 4. sampling -> samp fp16 (over q16; GEMM1 already consumed it)
  sample_kernel<<<(NB * QN) / 2, 256, 0, stream>>>(vals, offb, attnb, refp, samp);

  // 5. out projection: samp @ Wout_t + b_out -> d_out f32
  gemm_f16_kernel<2><<<dim3((NB * QN) / 64, 4), 256, 0, stream>>>(
      samp, Wout_t, b_out, nullptr, nullptr, nullptr, out);
}

// Round 6
// 77.602 us; speedup vs baseline: 5.8225x; 1.2345x over previous
//
#include <hip/hip_runtime.h>
#include <math.h>

#define NB 2
#define QN 8192
#define DIM 256
#define S_TOT 5440   // 4096+1024+256+64

typedef unsigned int uint32;
typedef _Float16 f16;
typedef __attribute__((ext_vector_type(8))) _Float16 h8;   // MFMA A/B frag (4 VGPR)
typedef __attribute__((ext_vector_type(2))) _Float16 h2;
typedef __attribute__((ext_vector_type(4))) float f32x4;   // MFMA C/D frag
typedef __attribute__((ext_vector_type(4))) uint32 u32x4;  // 16B staging

// ---------------------------------------------------------------------------
// Fused weight prep: transpose+convert all 3 weight mats in ONE launch.
// src f32 [256][S] -> dst f16 [S][256].
// tiles: [0,8) W_off->Wcat_t ; [8,12) W_attn->Wcat_t+256*256 ;
//        [12,20) W_val->Wval_t ; [20,28) W_out->Wout_t
// ---------------------------------------------------------------------------
__global__ __launch_bounds__(256) void prep_w_kernel(
    const float* __restrict__ W_off, const float* __restrict__ W_attn,
    const float* __restrict__ W_val, const float* __restrict__ W_out,
    f16* __restrict__ Wcat_t, f16* __restrict__ Wval_t, f16* __restrict__ Wout_t) {
  const int t = blockIdx.x;
  const float* src; f16* dst; int S, tb;
  if (t < 8)       { src = W_off;  dst = Wcat_t;           S = 256; tb = t; }
  else if (t < 12) { src = W_attn; dst = Wcat_t + 256*256; S = 128; tb = t - 8; }
  else if (t < 20) { src = W_val;  dst = Wval_t;           S = 256; tb = t - 12; }
  else             { src = W_out;  dst = Wout_t;           S = 256; tb = t - 20; }

  __shared__ float tile[32][33];
  const int tx = threadIdx.x & 31, ty = threadIdx.x >> 5;
  const int s0 = tb * 32, c0 = blockIdx.y * 32;
#pragma unroll
  for (int j = 0; j < 4; ++j) {
    const int c = c0 + ty + j * 8;
    tile[ty + j * 8][tx] = src[(size_t)c * S + s0 + tx];
  }
  __syncthreads();
#pragma unroll
  for (int j = 0; j < 4; ++j) {
    const int srow = s0 + ty + j * 8;
    dst[(size_t)srow * 256 + c0 + tx] = (f16)tile[tx][ty + j * 8];
  }
}

// ---------------------------------------------------------------------------
// Fused feat transpose: all 4 levels in ONE launch.
// feat_l f32 [b][256][HW] -> featT f16 [b][S_TOT][256].
// grid.x = 170 s-tiles (128 lvl0 + 32 + 8 + 2), grid.y = 8 c-tiles, grid.z = b.
// ---------------------------------------------------------------------------
__global__ __launch_bounds__(256) void tconv_feat_kernel(
    const float* __restrict__ f0, const float* __restrict__ f1,
    const float* __restrict__ f2, const float* __restrict__ f3,
    f16* __restrict__ featT) {
  const int t = blockIdx.x, b = blockIdx.z, c0 = blockIdx.y * 32;
  const float* src; int HW, soff, tb;
  if (t < 128)      { src = f0; HW = 4096; soff = 0;    tb = t; }
  else if (t < 160) { src = f1; HW = 1024; soff = 4096; tb = t - 128; }
  else if (t < 168) { src = f2; HW = 256;  soff = 5120; tb = t - 160; }
  else              { src = f3; HW = 64;   soff = 5376; tb = t - 168; }
  const int s0 = tb * 32;

  __shared__ float tile[32][33];
  const int tx = threadIdx.x & 31, ty = threadIdx.x >> 5;
  const float* sp = src + (size_t)b * 256 * HW;
#pragma unroll
  for (int j = 0; j < 4; ++j) {
    const int c = c0 + ty + j * 8;
    tile[ty + j * 8][tx] = sp[(size_t)c * HW + s0 + tx];
  }
  __syncthreads();
#pragma unroll
  for (int j = 0; j < 4; ++j) {
    const int srow = s0 + ty + j * 8;
    featT[((size_t)b * S_TOT + soff + srow) * 256 + c0 + tx] =
        (f16)tile[tx][ty + j * 8];
  }
}

// ---------------------------------------------------------------------------
// fp16 MFMA GEMM: C[M x N] = A[M x 256] @ Bt[N x 256]^T + bias.
// 64x64 tile, 4 waves (2x2), wave = 32x32 = 2x2 16x16x32 frags, whole-K LDS.
// XOR swizzle slot^(row&7): frag ds_read_b128 2-way (free).
// MODE 0: A f16; fp16 out o0 (stride 256), bias0              [vals]
// MODE 1: A f32 (query; fused convq). c0<256 -> f16 o0 (offsets, bias0);
//         c0>=256 -> f16 o1 (stride 128, logits, bias1)
// MODE 2: A f16; f32 out o2 (stride 256), bias0               [final]
// ---------------------------------------------------------------------------
template <int MODE>
__global__ __launch_bounds__(256) void gemm_f16_kernel(
    const f16* __restrict__ A, const float* __restrict__ Af32,
    const f16* __restrict__ Bt,
    const float* __restrict__ bias0, const float* __restrict__ bias1,
    f16* __restrict__ o0, f16* __restrict__ o1, float* __restrict__ o2) {
  __shared__ f16 As[64][256];
  __shared__ f16 Bs[64][256];
  const int tid = threadIdx.x;
  const size_t r0 = (size_t)blockIdx.x * 64;
  const size_t c0 = (size_t)blockIdx.y * 64;

  {  // stage tiles: 8 iters x 256 threads
    const f16* gb = Bt + c0 * 256;
    const int row = tid >> 5, slot = tid & 31;
#pragma unroll
    for (int i = 0; i < 8; ++i) {
      const int r = i * 8 + row;
      const int ph = (slot & 24) | ((slot ^ r) & 7);
      if constexpr (MODE == 1) {
        const float* ga = Af32 + (r0 + r) * 256 + slot * 8;
        const float4 u0 = *(const float4*)ga;
        const float4 u1 = *(const float4*)(ga + 4);
        h8 hv = {(f16)u0.x, (f16)u0.y, (f16)u0.z, (f16)u0.w,
                 (f16)u1.x, (f16)u1.y, (f16)u1.z, (f16)u1.w};
        *(h8*)&As[r][ph * 8] = hv;
      } else {
        *(u32x4*)&As[r][ph * 8] =
            *(const u32x4*)(A + (r0 + r) * 256 + slot * 8);
      }
      *(u32x4*)&Bs[r][ph * 8] = *(const u32x4*)(gb + (size_t)r * 256 + slot * 8);
    }
  }
  __syncthreads();

  const int wid = tid >> 6, lane = tid & 63;
  const int wr = (wid >> 1) * 32, wc = (wid & 1) * 32;
  const int l15 = lane & 15, l4 = lane >> 4;

  f32x4 acc[2][2] = {};
#pragma unroll
  for (int ks = 0; ks < 8; ++ks) {
    const int slot = ks * 4 + l4;
    h8 a[2], b[2];
#pragma unroll
    for (int m = 0; m < 2; ++m) {
      const int r = wr + m * 16 + l15;
      const int ph = (slot & 24) | ((slot ^ r) & 7);
      a[m] = *(const h8*)&As[r][ph * 8];
    }
#pragma unroll
    for (int n = 0; n < 2; ++n) {
      const int r = wc + n * 16 + l15;
      const int ph = (slot & 24) | ((slot ^ r) & 7);
      b[n] = *(const h8*)&Bs[r][ph * 8];
    }
#pragma unroll
    for (int m = 0; m < 2; ++m)
#pragma unroll
      for (int n = 0; n < 2; ++n)
        acc[m][n] = __builtin_amdgcn_mfma_f32_16x16x32_f16(a[m], b[n], acc[m][n], 0, 0, 0);
  }

  // C/D: col = lane&15, row = (lane>>4)*4 + reg
#pragma unroll
  for (int m = 0; m < 2; ++m)
#pragma unroll
    for (int n = 0; n < 2; ++n)
#pragma unroll
      for (int r = 0; r < 4; ++r) {
        const size_t row = r0 + wr + m * 16 + l4 * 4 + r;
        const size_t col = c0 + wc + n * 16 + l15;
        const float v = acc[m][n][r];
        if constexpr (MODE == 0) {
          o0[row * 256 + col] = (f16)(v + bias0[col]);
        } else if constexpr (MODE == 1) {
          if (c0 < 256)
            o0[row * 256 + col] = (f16)(v + bias0[col]);
          else
            o1[row * 128 + (col - 256)] = (f16)(v + bias1[col - 256]);
        } else {
          o2[row * 256 + col] = v + bias0[col];
        }
      }
}

// ---------------------------------------------------------------------------
// Sampling + softmax + weighted sum, fp16 values.
// Block = 2 queries; per query 8 heads x 16 lanes (grp).
// Phase 1: lane g = point g: softmax weight + bilinear {float4 w, int4 byteoff}
//          into padded LDS.
// Phase 2: lane (c4=g&3, pc=g>>2): channels 8*c4..8*c4+7, corner pc of every
//          point; 16 iters of {2x ds_read_b32 (conflict-free), 16B gather,
//          8 fma}; __shfl_xor(4|8) combines corners; pc==0 stores 16B f16.
// ---------------------------------------------------------------------------
__global__ __launch_bounds__(256) void sample_kernel(
    const f16* __restrict__ vals, const f16* __restrict__ offb,
    const f16* __restrict__ attnb, const float* __restrict__ refp,
    f16* __restrict__ samp) {
  const int tid = threadIdx.x;
  const int g = tid & 15;
  const int grp = tid >> 4;
  const int h = grp & 7;
  const int half = tid >> 7;
  const int bq = blockIdx.x * 2 + half;
  const int b = bq >> 13;

  __shared__ float4 wts[16][17];
  __shared__ int4 idxs[16][17];

  // ---- phase 1 ----
  const float rx = refp[(size_t)bq * 2 + 0];
  const float ry = refp[(size_t)bq * 2 + 1];

  float logit = (float)attnb[(size_t)bq * 128 + h * 16 + g];
  float m = logit;
#pragma unroll
  for (int mask = 1; mask < 16; mask <<= 1)
    m = fmaxf(m, __shfl_xor(m, mask, 16));
  const float e = __expf(logit - m);
  float ssum = e;
#pragma unroll
  for (int mask = 1; mask < 16; mask <<= 1)
    ssum += __shfl_xor(ssum, mask, 16);
  const float aw = e / ssum;

  const h2 ov = *(const h2*)(offb + (size_t)bq * 256 + h * 32 + g * 2);
  const int l = g >> 2;
  const int Wl = 64 >> l;
  const int loff = (l == 0) ? 0 : (l == 1) ? 4096 : (l == 2) ? 5120 : 5376;

  const float px = (rx + (float)ov[0]) * (float)Wl - 0.5f;
  const float py = (ry + (float)ov[1]) * (float)Wl - 0.5f;
  const float fx = floorf(px), fy = floorf(py);
  const float wx = px - fx, wy = py - fy;
  const int x0 = (int)fx, y0 = (int)fy;
  const int x1 = x0 + 1, y1 = y0 + 1;
  const float vx0 = (x0 >= 0 && x0 < Wl) ? 1.f : 0.f;
  const float vx1 = (x1 >= 0 && x1 < Wl) ? 1.f : 0.f;
  const float vy0 = (y0 >= 0 && y0 < Wl) ? 1.f : 0.f;
  const float vy1 = (y1 >= 0 && y1 < Wl) ? 1.f : 0.f;
  const int cx0 = min(max(x0, 0), Wl - 1), cx1 = min(max(x1, 0), Wl - 1);
  const int cy0 = min(max(y0, 0), Wl - 1), cy1 = min(max(y1, 0), Wl - 1);
  const int base = b * S_TOT + loff;
  idxs[grp][g] = make_int4((base + cy0 * Wl + cx0) * 512,
                           (base + cy0 * Wl + cx1) * 512,
                           (base + cy1 * Wl + cx0) * 512,
                           (base + cy1 * Wl + cx1) * 512);
  wts[grp][g] = make_float4(aw * (1.f - wx) * (1.f - wy) * vx0 * vy0,
                            aw * wx * (1.f - wy) * vx1 * vy0,
                            aw * (1.f - wx) * wy * vx0 * vy1,
                            aw * wx * wy * vx1 * vy1);
  __syncthreads();

  // ---- phase 2 ----
  const int c4 = g & 3, pc = g >> 2;
  const char* vb = (const char*)vals + (h * 64 + c4 * 16);
  float a[8] = {};
#pragma unroll
  for (int pt = 0; pt < 16; ++pt) {
    const float w = ((const float*)&wts[grp][pt])[pc];
    const int id = ((const int*)&idxs[grp][pt])[pc];
    const h8 v = *(const h8*)(vb + id);
#pragma unroll
    for (int k = 0; k < 8; ++k) a[k] = fmaf((float)v[k], w, a[k]);
  }
#pragma unroll
  for (int k = 0; k < 8; ++k) {
    a[k] += __shfl_xor(a[k], 4);
    a[k] += __shfl_xor(a[k], 8);
  }
  if (pc == 0) {
    h8 r;
#pragma unroll
    for (int k = 0; k < 8; ++k) r[k] = (f16)a[k];
    *(h8*)(samp + (size_t)bq * 256 + h * 32 + c4 * 8) = r;
  }
}

// ---------------------------------------------------------------------------
extern "C" void kernel_launch(void* const* d_in, const int* in_sizes, int n_in,
                              void* d_out, int out_size, void* d_ws, size_t ws_size,
                              hipStream_t stream) {
  const float* query = (const float*)d_in[0];
  const float* feat[4] = {(const float*)d_in[1], (const float*)d_in[2],
                          (const float*)d_in[3], (const float*)d_in[4]};
  const float* refp  = (const float*)d_in[5];
  const float* W_off = (const float*)d_in[6];
  const float* b_off = (const float*)d_in[7];
  const float* W_attn = (const float*)d_in[8];
  const float* b_attn = (const float*)d_in[9];
  const float* W_val = (const float*)d_in[10];
  const float* b_val = (const float*)d_in[11];
  const float* W_out = (const float*)d_in[12];
  const float* b_out = (const float*)d_in[13];
  float* out = (float*)d_out;

  // ---- workspace layout (f16 units; ~28.4 MB) ----
  f16* ws = (f16*)d_ws;
  f16* featT  = ws;                                  // [10880][256]  5.57MB
  f16* attnb  = featT;                               // ALIAS [16384][128]: GEMM1
                                                     // writes after GEMM2 read featT
  f16* vals   = featT + (size_t)NB * S_TOT * 256;    // [10880][256]  5.57MB
  f16* offb   = vals + (size_t)NB * S_TOT * 256;     // [16384][256]  8.4MB
  f16* samp   = offb + (size_t)NB * QN * 256;        // [16384][256]  8.4MB
  f16* Wcat_t = samp + (size_t)NB * QN * 256;        // [384][256]
  f16* Wval_t = Wcat_t + 384 * 256;                  // [256][256]
  f16* Wout_t = Wval_t + 256 * 256;                  // [256][256]

  // 1. weight prep (1 launch) + feat transpose (1 launch)
  prep_w_kernel<<<dim3(28, 8, 1), 256, 0, stream>>>(
      W_off, W_attn, W_val, W_out, Wcat_t, Wval_t, Wout_t);
  tconv_feat_kernel<<<dim3(170, 8, NB), 256, 0, stream>>>(
      feat[0], feat[1], feat[2], feat[3], featT);

  // 2. value projection: featT @ Wval_t + b_val -> vals f16   (before GEMM1!)
  gemm_f16_kernel<0><<<dim3((NB * S_TOT) / 64, 4), 256, 0, stream>>>(
      featT, nullptr, Wval_t, b_val, nullptr, vals, nullptr, nullptr);

  // 3. offset+logit projection, fused convq: query f32 @ Wcat_t
  //    -> offb f16 + attnb f16 (attnb overwrites featT, already consumed)
  gemm_f16_kernel<1><<<dim3((NB * QN) / 64, 6), 256, 0, stream>>>(
      nullptr, query, Wcat_t, b_off, b_attn, offb, attnb, nullptr);

  // 4. sampling -> samp f16
  sample_kernel<<<(NB * QN) / 2, 256, 0, stream>>>(vals, offb, attnb, refp, samp);

  // 5. out projection: samp @ Wout_t + b_out -> d_out f32
  gemm_f16_kernel<2><<<dim3((NB * QN) / 64, 4), 256, 0, stream>>>(
      samp, nullptr, Wout_t, b_out, nullptr, nullptr, nullptr, out);
}